// Round 8
// baseline (298.550 us; speedup 1.0000x reference)
//
#include <hip/hip_runtime.h>
#include <hip/hip_bf16.h>

typedef unsigned short u16;
typedef unsigned int u32;
typedef unsigned char u8;
typedef __bf16 bf16x8 __attribute__((ext_vector_type(8)));
typedef float f32x4 __attribute__((ext_vector_type(4)));
typedef float f32x2 __attribute__((ext_vector_type(2)));

#define DIM 256
#define BN_SCALE 0.9999950000374997f // 1/sqrt(1 + 1e-5)

__device__ __forceinline__ float bf2f(u16 u) {
    union { unsigned u; float f; } c; c.u = ((unsigned)u) << 16; return c.f;
}
__device__ __forceinline__ u16 f2bf(float f) {
    union { float f; unsigned u; } c; c.f = f;
    unsigned u = c.u;
    unsigned r = (u + 0x7FFFu + ((u >> 16) & 1u)) >> 16;  // RNE
    return (u16)r;
}
__device__ __forceinline__ float asf(unsigned u) {
    union { unsigned u; float f; } c; c.u = u; return c.f;
}
__device__ __forceinline__ void cvt8(int4 v, float* f) {
    unsigned a0 = (unsigned)v.x, a1 = (unsigned)v.y, a2 = (unsigned)v.z, a3 = (unsigned)v.w;
    f[0] = asf(a0 << 16); f[1] = asf(a0 & 0xFFFF0000u);
    f[2] = asf(a1 << 16); f[3] = asf(a1 & 0xFFFF0000u);
    f[4] = asf(a2 << 16); f[5] = asf(a2 & 0xFFFF0000u);
    f[6] = asf(a3 << 16); f[7] = asf(a3 & 0xFFFF0000u);
}
__device__ __forceinline__ void dec4(unsigned u, float* f) {
    f32x2 lo = __builtin_amdgcn_cvt_pk_f32_fp8((int)u, false);
    f32x2 hi = __builtin_amdgcn_cvt_pk_f32_fp8((int)u, true);
    f[0] = lo.x; f[1] = lo.y; f[2] = hi.x; f[3] = hi.y;
}
__device__ __forceinline__ unsigned pack4(float a, float b, float c, float d) {
    int u = __builtin_amdgcn_cvt_pk_fp8_f32(a, b, 0, false);
    u = __builtin_amdgcn_cvt_pk_fp8_f32(c, d, u, true);
    return (unsigned)u;
}
__device__ __forceinline__ void gl_lds16(const u16* g, u16* l) {
    __builtin_amdgcn_global_load_lds(
        (__attribute__((address_space(1))) const u32*)(const void*)g,
        (__attribute__((address_space(3))) u32*)(void*)l, 16, 0, 0);
}

// wave-uniform dtype detect: .x = floats-are-bf16, .y = edges-are-int64
__device__ __forceinline__ int2 detect_inline(const u16* __restrict__ xu,
                                              const long long* __restrict__ e64) {
    int lane = threadIdx.x & 63;
    int pl = 0;
#pragma unroll
    for (int j = 0; j < 4; ++j) {
        u16 u = xu[lane * 4 + j];
        int ex = (u >> 7) & 0xFF;
        pl += (u == 0 || (ex >= 115 && ex <= 131)) ? 1 : 0;
    }
#pragma unroll
    for (int o = 32; o; o >>= 1) pl += __shfl_xor(pl, o, 64);
    long long hi = e64[lane] >> 32;
    unsigned long long b = __ballot(hi == 0);
    int2 r; r.x = (pl >= 200) ? 1 : 0; r.y = (b == ~0ULL) ? 1 : 0;
    return r;
}

// ---------------- fused prep: weight transpose (blocks < T) + arena convert (blocks >= T) ----------------
struct CvtDesc { const void* src[9]; int cum[10]; };
struct TDesc { const void* baseL; const void* baseR; int L; };
__global__ __launch_bounds__(256) void k_prep(
    CvtDesc cd, TDesc td, const void* w0, const void* w1, const void* w2, const void* w3,
    const u16* __restrict__ xu, const long long* __restrict__ e64,
    u16* __restrict__ arena, int total, int* __restrict__ deg, int N,
    u16* __restrict__ WT, int Tblocks) {
    __shared__ u16 t[64][72];
    int2 fl = detect_inline(xu, e64);
    if ((int)blockIdx.x < Tblocks) {
        int m = blockIdx.x >> 4, tl = blockIdx.x & 15;
        int tr = (tl >> 2) * 64, tc = (tl & 3) * 64;
        const void* S;
        size_t eoff = 0;
        if (m < 4)             S = (m == 0) ? w0 : (m == 1) ? w1 : (m == 2) ? w2 : w3;
        else if (m < 4 + td.L) { S = td.baseL; eoff = (size_t)(m - 4) * DIM * DIM; }
        else                   { S = td.baseR; eoff = (size_t)(m - 4 - td.L) * DIM * DIM; }
        u16* D = WT + (size_t)m * DIM * DIM;
        int r = threadIdx.x >> 2, cs = (threadIdx.x & 3) * 16;
        size_t src_idx = eoff + (size_t)(tr + r) * 256 + tc + cs;
        if (fl.x) {
            const u16* S16 = (const u16*)S + src_idx;
            *(int4*)&t[r][cs]     = *(const int4*)S16;
            *(int4*)&t[r][cs + 8] = *(const int4*)(S16 + 8);
        } else {
            const float* SF = (const float*)S + src_idx;
            u16 tmp[16];
#pragma unroll
            for (int q = 0; q < 4; ++q) {
                float4 v = *(const float4*)(SF + q * 4);
                tmp[q * 4] = f2bf(v.x); tmp[q * 4 + 1] = f2bf(v.y);
                tmp[q * 4 + 2] = f2bf(v.z); tmp[q * 4 + 3] = f2bf(v.w);
            }
            *(int4*)&t[r][cs]     = *(const int4*)&tmp[0];
            *(int4*)&t[r][cs + 8] = *(const int4*)&tmp[8];
        }
        __syncthreads();
        u16 tmp[16];
#pragma unroll
        for (int j = 0; j < 16; ++j) tmp[j] = t[cs + j][r];
        *(int4*)&D[(tc + r) * 256 + tr + cs]     = *(int4*)&tmp[0];
        *(int4*)&D[(tc + r) * 256 + tr + cs + 8] = *(int4*)&tmp[8];
    } else {
        int i = ((int)blockIdx.x - Tblocks) * 256 + threadIdx.x;
        if (i < N) deg[i] = 0;
        if (i >= total) return;
        int t2 = 0;
        while (i >= cd.cum[t2 + 1]) ++t2;
        int j = i - cd.cum[t2];
        u16 v;
        if (fl.x) v = ((const u16*)cd.src[t2])[j];
        else      v = f2bf(((const float*)cd.src[t2])[j]);
        arena[i] = v;
    }
}

// ---------------- degree histogram / CSR from ORIGINAL edges ----------------
__global__ void k_edges(const int* __restrict__ ei32, const u16* __restrict__ xu,
                        int* __restrict__ deg, int E) {
    int2 fl = detect_inline(xu, (const long long*)ei32);
    int e = blockIdx.x * 256 + threadIdx.x;
    if (e >= E) return;
    const long long* ei64 = (const long long*)ei32;
    int d = fl.y ? (int)ei64[E + e] : ei32[E + e];
    atomicAdd(&deg[d], 1);
}

__global__ __launch_bounds__(1024) void k_scan(const int* __restrict__ deg,
                                               int* __restrict__ offs,
                                               int* __restrict__ cursor, int N, int E) {
    __shared__ int s[1024];
    int t = threadIdx.x;
    int P = (N + 1023) >> 10;
    int base = t * P;
    int run = 0;
    for (int j = 0; j < P; ++j) { int idx = base + j; if (idx < N) run += deg[idx]; }
    s[t] = run;
    __syncthreads();
    int total = run;
    for (int off = 1; off < 1024; off <<= 1) {
        int v = 0;
        if (t >= off) v = s[t - off];
        __syncthreads();
        if (t >= off) s[t] += v;
        __syncthreads();
    }
    int r = s[t] - total;
    for (int j = 0; j < P; ++j) {
        int idx = base + j;
        if (idx < N) { offs[idx] = r; cursor[idx] = r; r += deg[idx]; }
    }
    if (t == 0) offs[N] = E;
}

__global__ void k_fill(const int* __restrict__ ei32, const u16* __restrict__ xu,
                       int* __restrict__ cursor, int* __restrict__ csr, int E) {
    int2 fl = detect_inline(xu, (const long long*)ei32);
    int e = blockIdx.x * 256 + threadIdx.x;
    if (e >= E) return;
    const long long* ei64 = (const long long*)ei32;
    int s = fl.y ? (int)ei64[e]     : ei32[e];
    int d = fl.y ? (int)ei64[E + e] : ei32[E + e];
    int pos = atomicAdd(&cursor[d], 1);
    csr[pos] = s;
}

// ---------------- fused QKVS GEMM + kv8 fp8 side-pack ----------------
__global__ __launch_bounds__(256) void gemm_qkvs(
    const u16* __restrict__ x, const u16* __restrict__ WT,
    const u16* __restrict__ bias, u16* __restrict__ out,
    u8* __restrict__ kv8, int M) {
    __shared__ __align__(16) u16 lds[16384];
    u16* As = lds;
    u16* Bs = lds + 8192;
    int tid = threadIdx.x, w = tid >> 6, lane = tid & 63;
    int l15 = lane & 15, quad = lane >> 4;
    int lr = lane >> 3, lc = lane & 7;
    int bm0 = blockIdx.x * 128, bn0 = blockIdx.y * 128;
    f32x4 acc[4][4];
#pragma unroll
    for (int a = 0; a < 4; ++a)
#pragma unroll
        for (int b = 0; b < 4; ++b) acc[a][b] = (f32x4){0.f, 0.f, 0.f, 0.f};

    for (int k0 = 0; k0 < 256; k0 += 64) {
#pragma unroll
        for (int j = 0; j < 4; ++j) {
            int ar = (w * 4 + j) * 8 + lr;
            int grow = bm0 + ar; if (grow >= M) grow = M - 1;
            gl_lds16(x + (size_t)grow * 256 + k0 + lc * 8, &As[(w * 4 + j) * 512]);
        }
#pragma unroll
        for (int j = 0; j < 4; ++j) {
            int nr = (w * 4 + j) * 8 + lr;
            gl_lds16(WT + (size_t)(bn0 + nr) * 256 + k0 + lc * 8, &Bs[(w * 4 + j) * 512]);
        }
        __syncthreads();
        int wm = w & 1, wn = w >> 1;
#pragma unroll
        for (int s = 0; s < 2; ++s) {
            bf16x8 a[4], b[4];
#pragma unroll
            for (int t = 0; t < 4; ++t)
                a[t] = *(const bf16x8*)&As[(wm * 64 + t * 16 + l15) * 64 + s * 32 + quad * 8];
#pragma unroll
            for (int t = 0; t < 4; ++t)
                b[t] = *(const bf16x8*)&Bs[(wn * 64 + t * 16 + l15) * 64 + s * 32 + quad * 8];
#pragma unroll
            for (int rt = 0; rt < 4; ++rt)
#pragma unroll
                for (int ct = 0; ct < 4; ++ct)
                    acc[rt][ct] = __builtin_amdgcn_mfma_f32_16x16x32_bf16(a[rt], b[ct], acc[rt][ct], 0, 0, 0);
        }
        __syncthreads();
    }
    int wm = w & 1, wn = w >> 1;
    u16* oL = lds + w * 4096;
#pragma unroll
    for (int rt = 0; rt < 4; ++rt)
#pragma unroll
        for (int ct = 0; ct < 4; ++ct) {
            int col = bn0 + wn * 64 + ct * 16 + l15;
            float bv = bf2f(bias[col]);
#pragma unroll
            for (int r = 0; r < 4; ++r)
                oL[(rt * 16 + quad * 4 + r) * 64 + ct * 16 + l15] = f2bf(acc[rt][ct][r] + bv);
        }
    __syncthreads();
    int c0 = bn0 + wn * 64 + lc * 8;
#pragma unroll
    for (int j = 0; j < 8; ++j) {
        int orow = j * 8 + lr;
        int grow = bm0 + wm * 64 + orow;
        if (grow < M) {
            int4 hv = *(const int4*)&oL[orow * 64 + lc * 8];
            *(int4*)&out[(size_t)grow * 1024 + c0] = hv;
            if (c0 >= 256 && c0 < 768) {
                float f[8]; cvt8(hv, f);
                uint2 o8;
                o8.x = pack4(f[0], f[1], f[2], f[3]);
                o8.y = pack4(f[4], f[5], f[6], f[7]);
                *(uint2*)(kv8 + (size_t)grow * 512 + (c0 - 256)) = o8;
            }
        }
    }
}

// ---------------- fused attention: 16-edge unroll, all gathers hoisted ----------------
__device__ __forceinline__ float dotk2(uint4 k0, uint4 k1, const float* qf) {
    unsigned kw[8] = {k0.x, k0.y, k0.z, k0.w, k1.x, k1.y, k1.z, k1.w};
    float p = 0.f;
#pragma unroll
    for (int j = 0; j < 8; ++j) {
        float t[4]; dec4(kw[j], t);
        p += qf[j * 4] * t[0] + qf[j * 4 + 1] * t[1] + qf[j * 4 + 2] * t[2] + qf[j * 4 + 3] * t[3];
    }
    return p;
}
__device__ __forceinline__ void accv2(uint4 v0, uint4 v1, float w, float* acc) {
    unsigned vw[8] = {v0.x, v0.y, v0.z, v0.w, v1.x, v1.y, v1.z, v1.w};
#pragma unroll
    for (int j = 0; j < 8; ++j) {
        float t[4]; dec4(vw[j], t);
        acc[j * 4]     += w * t[0];
        acc[j * 4 + 1] += w * t[1];
        acc[j * 4 + 2] += w * t[2];
        acc[j * 4 + 3] += w * t[3];
    }
}

__global__ __launch_bounds__(256) void k_attn(const u16* __restrict__ qkvs,
                                              const u8* __restrict__ kv8,
                                              const int* __restrict__ csr,
                                              const int* __restrict__ offs,
                                              u16* __restrict__ hb,
                                              u8* __restrict__ h8, int N) {
    int wv = threadIdx.x >> 6, lane = threadIdx.x & 63;
    int i = blockIdx.x * 4 + wv;
    if (i >= N) return;
    int sub = lane & 7, e8 = lane >> 3;
    size_t row = (size_t)i * 1024;

    float qf[32];
    {
        const u16* qp = qkvs + row + sub * 32;
#pragma unroll
        for (int j = 0; j < 4; ++j) {
            int4 v = *(const int4*)(qp + j * 8);
            float t[8]; cvt8(v, t);
#pragma unroll
            for (int d = 0; d < 8; ++d) qf[j * 8 + d] = t[d] * 0.0625f;
        }
    }
    int e0 = offs[i], e1 = offs[i + 1];
    float m = -1e30f, denom = 0.f;
    float acc[32];
#pragma unroll
    for (int j = 0; j < 32; ++j) acc[j] = 0.f;

    for (int base = e0; base < e1; base += 16) {
        int eA = base + e8, eB = base + 8 + e8;
        int sA = csr[(eA < e1) ? eA : (e1 - 1)];
        int sB = csr[(eB < e1) ? eB : (e1 - 1)];
        const u8* pA = kv8 + (size_t)sA * 512 + sub * 32;
        const u8* pB = kv8 + (size_t)sB * 512 + sub * 32;
        uint4 kA0 = *(const uint4*)pA;
        uint4 kA1 = *(const uint4*)(pA + 16);
        uint4 vA0 = *(const uint4*)(pA + 256);
        uint4 vA1 = *(const uint4*)(pA + 272);
        uint4 kB0 = *(const uint4*)pB;
        uint4 kB1 = *(const uint4*)(pB + 16);
        uint4 vB0 = *(const uint4*)(pB + 256);
        uint4 vB1 = *(const uint4*)(pB + 272);
        float pa = dotk2(kA0, kA1, qf);
        float pb = dotk2(kB0, kB1, qf);
        pa += __shfl_xor(pa, 1, 64); pb += __shfl_xor(pb, 1, 64);
        pa += __shfl_xor(pa, 2, 64); pb += __shfl_xor(pb, 2, 64);
        pa += __shfl_xor(pa, 4, 64); pb += __shfl_xor(pb, 4, 64);
        if (eA >= e1) pa = -1e30f;
        if (eB >= e1) pb = -1e30f;
        float pm = fmaxf(pa, pb);
        pm = fmaxf(pm, __shfl_xor(pm, 8, 64));
        pm = fmaxf(pm, __shfl_xor(pm, 16, 64));
        pm = fmaxf(pm, __shfl_xor(pm, 32, 64));
        if (pm > m) {
            float sc = __expf(m - pm);
            denom *= sc;
#pragma unroll
            for (int j = 0; j < 32; ++j) acc[j] *= sc;
            m = pm;
        }
        float wA = __expf(pa - m);
        float wB = __expf(pb - m);
        denom += wA + wB;
        accv2(vA0, vA1, wA, acc);
        accv2(vB0, vB1, wB, acc);
    }
    denom += __shfl_xor(denom, 8, 64);
    denom += __shfl_xor(denom, 16, 64);
    denom += __shfl_xor(denom, 32, 64);
    float inv = (denom > 0.f) ? 1.f / denom : 0.f;
#pragma unroll
    for (int j = 0; j < 32; ++j) {
        acc[j] += __shfl_xor(acc[j], 8, 64);
        acc[j] += __shfl_xor(acc[j], 16, 64);
        acc[j] += __shfl_xor(acc[j], 32, 64);
    }
    if (e8 == 0) {
        const u16* skp = qkvs + row + 768 + sub * 32;
        float h[32];
#pragma unroll
        for (int j = 0; j < 4; ++j) {
            int4 sv = *(const int4*)(skp + j * 8);
            float t[8]; cvt8(sv, t);
            u16 o[8];
#pragma unroll
            for (int d = 0; d < 8; ++d) {
                float hv = fmaxf(acc[j * 8 + d] * inv + t[d], 0.f);
                h[j * 8 + d] = hv;
                o[d] = f2bf(hv);
            }
            *(int4*)(hb + (size_t)i * 256 + sub * 32 + j * 8) = *(const int4*)o;
        }
        uint4 p0, p1;
        p0.x = pack4(h[0], h[1], h[2], h[3]);   p0.y = pack4(h[4], h[5], h[6], h[7]);
        p0.z = pack4(h[8], h[9], h[10], h[11]); p0.w = pack4(h[12], h[13], h[14], h[15]);
        p1.x = pack4(h[16], h[17], h[18], h[19]); p1.y = pack4(h[20], h[21], h[22], h[23]);
        p1.z = pack4(h[24], h[25], h[26], h[27]); p1.w = pack4(h[28], h[29], h[30], h[31]);
        *(uint4*)(h8 + (size_t)i * 256 + sub * 32) = p0;
        *(uint4*)(h8 + (size_t)i * 256 + sub * 32 + 16) = p1;
    }
}

// ---------------- SAGE mean: one wave per node, 16 edges in flight ----------------
__global__ __launch_bounds__(256) void k_agg(const u8* __restrict__ h8,
                                             const int* __restrict__ csr,
                                             const int* __restrict__ offs,
                                             u16* __restrict__ mean_out, int N) {
    int w = threadIdx.x >> 6, lane = threadIdx.x & 63;
    int i = blockIdx.x * 4 + w;
    if (i >= N) return;
    int g = lane >> 4, sub = lane & 15;
    int e0 = offs[i], e1 = offs[i + 1];
    float acc[16];
#pragma unroll
    for (int d = 0; d < 16; ++d) acc[d] = 0.f;
    int e = e0;
    for (; e + 16 <= e1; e += 16) {
        int s0 = csr[e + g], s1 = csr[e + 4 + g], s2 = csr[e + 8 + g], s3 = csr[e + 12 + g];
        uint4 r0 = *(const uint4*)(h8 + (size_t)s0 * 256 + sub * 16);
        uint4 r1 = *(const uint4*)(h8 + (size_t)s1 * 256 + sub * 16);
        uint4 r2 = *(const uint4*)(h8 + (size_t)s2 * 256 + sub * 16);
        uint4 r3 = *(const uint4*)(h8 + (size_t)s3 * 256 + sub * 16);
        float f0[16], f1[16], f2[16], f3[16];
        dec4(r0.x, f0); dec4(r0.y, f0 + 4); dec4(r0.z, f0 + 8); dec4(r0.w, f0 + 12);
        dec4(r1.x, f1); dec4(r1.y, f1 + 4); dec4(r1.z, f1 + 8); dec4(r1.w, f1 + 12);
        dec4(r2.x, f2); dec4(r2.y, f2 + 4); dec4(r2.z, f2 + 8); dec4(r2.w, f2 + 12);
        dec4(r3.x, f3); dec4(r3.y, f3 + 4); dec4(r3.z, f3 + 8); dec4(r3.w, f3 + 12);
#pragma unroll
        for (int d = 0; d < 16; ++d) acc[d] += (f0[d] + f1[d]) + (f2[d] + f3[d]);
    }
    for (; e + 4 <= e1; e += 4) {
        int s0 = csr[e + g];
        uint4 r0 = *(const uint4*)(h8 + (size_t)s0 * 256 + sub * 16);
        float f0[16];
        dec4(r0.x, f0); dec4(r0.y, f0 + 4); dec4(r0.z, f0 + 8); dec4(r0.w, f0 + 12);
#pragma unroll
        for (int d = 0; d < 16; ++d) acc[d] += f0[d];
    }
    if (e + g < e1) {
        int s0 = csr[e + g];
        uint4 r0 = *(const uint4*)(h8 + (size_t)s0 * 256 + sub * 16);
        float f0[16];
        dec4(r0.x, f0); dec4(r0.y, f0 + 4); dec4(r0.z, f0 + 8); dec4(r0.w, f0 + 12);
#pragma unroll
        for (int d = 0; d < 16; ++d) acc[d] += f0[d];
    }
#pragma unroll
    for (int d = 0; d < 16; ++d) {
        acc[d] += __shfl_xor(acc[d], 16, 64);
        acc[d] += __shfl_xor(acc[d], 32, 64);
    }
    if (g == 0) {
        int dg = e1 - e0; if (dg < 1) dg = 1;
        float inv = 1.f / (float)dg;
        u16 o16[16];
#pragma unroll
        for (int d = 0; d < 16; ++d) o16[d] = f2bf(acc[d] * inv);
        u16* dst = mean_out + (size_t)i * 256 + sub * 16;
        *(int4*)dst = *(const int4*)&o16[0];
        *(int4*)(dst + 8) = *(const int4*)&o16[8];
    }
}

// ---------------- SAGE GEMM (K=512) + BN / gated residual / relu ----------------
__global__ __launch_bounds__(256) void gemm_sage(
    const u16* __restrict__ meanA, const u16* __restrict__ hin,
    const u16* __restrict__ WlT, const u16* __restrict__ WrT,
    const u16* __restrict__ bl, const u16* __restrict__ gamma,
    const u16* __restrict__ beta, const u16* __restrict__ alpha,
    u16* __restrict__ hout, u8* __restrict__ h8out, float* __restrict__ fout, int M) {
    __shared__ __align__(16) u16 lds[12288];
    u16* As = lds;
    u16* Bs = lds + 8192;
    int tid = threadIdx.x, w = tid >> 6, lane = tid & 63;
    int l15 = lane & 15, quad = lane >> 4;
    int lr = lane >> 3, lc = lane & 7;
    int bm0 = blockIdx.x * 128, n0 = blockIdx.y * 64;
    f32x4 acc[2][4];
#pragma unroll
    for (int a = 0; a < 2; ++a)
#pragma unroll
        for (int b = 0; b < 4; ++b) acc[a][b] = (f32x4){0.f, 0.f, 0.f, 0.f};

    for (int k0 = 0; k0 < 512; k0 += 64) {
        const u16* Asrc = (k0 < 256) ? meanA : hin;
        const u16* Bsrc = (k0 < 256) ? WlT : WrT;
        int kc = k0 & 255;
#pragma unroll
        for (int j = 0; j < 4; ++j) {
            int ar = (w * 4 + j) * 8 + lr;
            int grow = bm0 + ar; if (grow >= M) grow = M - 1;
            gl_lds16(Asrc + (size_t)grow * 256 + kc + lc * 8, &As[(w * 4 + j) * 512]);
        }
#pragma unroll
        for (int j = 0; j < 2; ++j) {
            int nr = (w * 2 + j) * 8 + lr;
            gl_lds16(Bsrc + (size_t)(n0 + nr) * 256 + kc + lc * 8, &Bs[(w * 2 + j) * 512]);
        }
        __syncthreads();
#pragma unroll
        for (int s = 0; s < 2; ++s) {
            bf16x8 a[2], b[4];
#pragma unroll
            for (int t = 0; t < 2; ++t)
                a[t] = *(const bf16x8*)&As[(w * 32 + t * 16 + l15) * 64 + s * 32 + quad * 8];
#pragma unroll
            for (int t = 0; t < 4; ++t)
                b[t] = *(const bf16x8*)&Bs[(t * 16 + l15) * 64 + s * 32 + quad * 8];
#pragma unroll
            for (int rt = 0; rt < 2; ++rt)
#pragma unroll
                for (int ct = 0; ct < 4; ++ct)
                    acc[rt][ct] = __builtin_amdgcn_mfma_f32_16x16x32_bf16(a[rt], b[ct], acc[rt][ct], 0, 0, 0);
        }
        __syncthreads();
    }

    float al = 1.f / (1.f + __expf(-bf2f(alpha[0])));
    float alc = 1.f - al;
    u16* oL = lds + w * 2048;
#pragma unroll
    for (int rt = 0; rt < 2; ++rt)
#pragma unroll
        for (int ct = 0; ct < 4; ++ct) {
            int col = n0 + ct * 16 + l15;
            float g  = bf2f(gamma[col]) * BN_SCALE;
            float be = bf2f(beta[col]);
            float bb = bf2f(bl[col]);
#pragma unroll
            for (int r = 0; r < 4; ++r) {
                int grow = bm0 + w * 32 + rt * 16 + quad * 4 + r;
                float z = (acc[rt][ct][r] + bb) * g + be;
                float prev = (grow < M) ? bf2f(hin[(size_t)grow * 256 + col]) : 0.f;
                z = al * z + alc * prev;
                z = fmaxf(z, 0.f);
                oL[(rt * 16 + quad * 4 + r) * 64 + ct * 16 + l15] = f2bf(z);
                if (fout && grow < M) fout[(size_t)grow * 256 + col] = z;
            }
        }
    if (!hout) return;
    __syncthreads();
#pragma unroll
    for (int j = 0; j < 4; ++j) {
        int orow = j * 8 + lr;
        int grow = bm0 + w * 32 + orow;
        if (grow < M) {
            int4 hv = *(const int4*)&oL[orow * 64 + lc * 8];
            *(int4*)&hout[(size_t)grow * 256 + n0 + lc * 8] = hv;
            float f[8]; cvt8(hv, f);
            uint2 o8;
            o8.x = pack4(f[0], f[1], f[2], f[3]);
            o8.y = pack4(f[4], f[5], f[6], f[7]);
            *(uint2*)(h8out + (size_t)grow * 256 + n0 + lc * 8) = o8;
        }
    }
}

extern "C" void kernel_launch(void* const* d_in, const int* in_sizes, int n_in,
                              void* d_out, int out_size, void* d_ws, size_t ws_size,
                              hipStream_t stream) {
    int N = in_sizes[0] / DIM;
    int E = in_sizes[1] / 2;
    int L = in_sizes[10] / (DIM * DIM);

    const u16* xu = (const u16*)d_in[0];
    const long long* e64 = (const long long*)d_in[1];

    const int map9[9] = {0, 3, 5, 7, 9, 11, 13, 14, 15};
    CvtDesc cd;
    cd.cum[0] = 0;
    for (int t = 0; t < 9; ++t) {
        cd.src[t] = d_in[map9[t]];
        cd.cum[t + 1] = cd.cum[t] + in_sizes[map9[t]];
    }
    int total = cd.cum[9];

    char* ws = (char*)d_ws;
    size_t off = 0;
    auto take = [&](size_t bytes) { size_t c = off; off = (off + bytes + 255) & ~255ULL; return c; };

    u16* arena  = (u16*)(ws + take((size_t)total * 2));
    u16* WT     = (u16*)(ws + take((size_t)(4 + 2 * L) * DIM * DIM * 2));
    int* csr    = (int*)(ws + take((size_t)E * 4));
    int* deg    = (int*)(ws + take((size_t)N * 4));
    int* offs   = (int*)(ws + take((size_t)(N + 1) * 4));
    int* cursor = (int*)(ws + take((size_t)N * 4));
    u16* hB0    = (u16*)(ws + take((size_t)N * DIM * 2));
    u8*  kv8    = (u8*)(ws + take((size_t)N * 512));
    u8*  h8     = (u8*)(ws + take((size_t)N * 256));
    u16* qkvsB  = (u16*)(ws + take((size_t)N * 1024 * 2)); // dead after k_attn
    u16* meanB  = qkvsB;                                   // overlay
    u16* hB1    = qkvsB + (size_t)N * DIM;                 // overlay
    (void)ws_size; (void)n_in; (void)out_size;

    const u16* xb    = arena + cd.cum[0];
    const u16* biasF = arena + cd.cum[1];   // bq|bk|bv|bs contiguous
    const u16* blb   = arena + cd.cum[5];
    const u16* gmb   = arena + cd.cum[6];
    const u16* btb   = arena + cd.cum[7];
    const u16* alb   = arena + cd.cum[8];

    TDesc td;
    td.baseL = d_in[10]; td.baseR = d_in[12]; td.L = L;
    int Tblocks = (4 + 2 * L) * 16;
    int Cblocks = (total + 255) / 256;
    k_prep<<<Tblocks + Cblocks, 256, 0, stream>>>(cd, td, d_in[2], d_in[4], d_in[6], d_in[8],
                                                  xu, e64, arena, total, deg, N, WT, Tblocks);

    int eb = (E + 255) / 256;
    k_edges<<<eb, 256, 0, stream>>>((const int*)d_in[1], xu, deg, E);
    k_scan<<<1, 1024, 0, stream>>>(deg, offs, cursor, N, E);
    k_fill<<<eb, 256, 0, stream>>>((const int*)d_in[1], xu, cursor, csr, E);

    int Mb128 = (N + 127) / 128;
    gemm_qkvs<<<dim3(Mb128, 8), 256, 0, stream>>>(xb, WT, biasF, qkvsB, kv8, N);
    k_attn<<<(N + 3) / 4, 256, 0, stream>>>(qkvsB, kv8, csr, offs, hB0, h8, N);

    for (int l = 0; l < L; ++l) {
        const u16* hin = (l & 1) ? hB1 : hB0;
        u16* hout      = (l == L - 1) ? nullptr : ((l & 1) ? hB0 : hB1);
        u8*  h8o       = (l == L - 1) ? nullptr : h8;
        float* fout    = (l == L - 1) ? (float*)d_out : nullptr;
        k_agg<<<(N + 3) / 4, 256, 0, stream>>>(h8, csr, offs, meanB, N);
        gemm_sage<<<dim3(Mb128, 4), 256, 0, stream>>>(
            meanB, hin, WT + (size_t)(4 + l) * DIM * DIM, WT + (size_t)(4 + L + l) * DIM * DIM,
            blb + (size_t)l * DIM, gmb + (size_t)l * DIM, btb + (size_t)l * DIM,
            alb, hout, h8o, fout, N);
    }
}

// Round 9
// 289.458 us; speedup vs baseline: 1.0314x; 1.0314x over previous
//
#include <hip/hip_runtime.h>
#include <hip/hip_bf16.h>

typedef unsigned short u16;
typedef unsigned int u32;
typedef unsigned char u8;
typedef __bf16 bf16x8 __attribute__((ext_vector_type(8)));
typedef float f32x4 __attribute__((ext_vector_type(4)));
typedef float f32x2 __attribute__((ext_vector_type(2)));

#define DIM 256
#define BN_SCALE 0.9999950000374997f // 1/sqrt(1 + 1e-5)

__device__ __forceinline__ float bf2f(u16 u) {
    union { unsigned u; float f; } c; c.u = ((unsigned)u) << 16; return c.f;
}
__device__ __forceinline__ u16 f2bf(float f) {
    union { float f; unsigned u; } c; c.f = f;
    unsigned u = c.u;
    unsigned r = (u + 0x7FFFu + ((u >> 16) & 1u)) >> 16;  // RNE
    return (u16)r;
}
__device__ __forceinline__ float asf(unsigned u) {
    union { unsigned u; float f; } c; c.u = u; return c.f;
}
__device__ __forceinline__ void cvt8(int4 v, float* f) {
    unsigned a0 = (unsigned)v.x, a1 = (unsigned)v.y, a2 = (unsigned)v.z, a3 = (unsigned)v.w;
    f[0] = asf(a0 << 16); f[1] = asf(a0 & 0xFFFF0000u);
    f[2] = asf(a1 << 16); f[3] = asf(a1 & 0xFFFF0000u);
    f[4] = asf(a2 << 16); f[5] = asf(a2 & 0xFFFF0000u);
    f[6] = asf(a3 << 16); f[7] = asf(a3 & 0xFFFF0000u);
}
__device__ __forceinline__ void dec4(unsigned u, float* f) {
    f32x2 lo = __builtin_amdgcn_cvt_pk_f32_fp8((int)u, false);
    f32x2 hi = __builtin_amdgcn_cvt_pk_f32_fp8((int)u, true);
    f[0] = lo.x; f[1] = lo.y; f[2] = hi.x; f[3] = hi.y;
}
__device__ __forceinline__ unsigned pack4(float a, float b, float c, float d) {
    int u = __builtin_amdgcn_cvt_pk_fp8_f32(a, b, 0, false);
    u = __builtin_amdgcn_cvt_pk_fp8_f32(c, d, u, true);
    return (unsigned)u;
}
__device__ __forceinline__ void gl_lds16(const u16* g, u16* l) {
    __builtin_amdgcn_global_load_lds(
        (__attribute__((address_space(1))) const u32*)(const void*)g,
        (__attribute__((address_space(3))) u32*)(void*)l, 16, 0, 0);
}

// wave-uniform dtype detect: .x = floats-are-bf16, .y = edges-are-int64
__device__ __forceinline__ int2 detect_inline(const u16* __restrict__ xu,
                                              const long long* __restrict__ e64) {
    int lane = threadIdx.x & 63;
    int pl = 0;
#pragma unroll
    for (int j = 0; j < 4; ++j) {
        u16 u = xu[lane * 4 + j];
        int ex = (u >> 7) & 0xFF;
        pl += (u == 0 || (ex >= 115 && ex <= 131)) ? 1 : 0;
    }
#pragma unroll
    for (int o = 32; o; o >>= 1) pl += __shfl_xor(pl, o, 64);
    long long hi = e64[lane] >> 32;
    unsigned long long b = __ballot(hi == 0);
    int2 r; r.x = (pl >= 200) ? 1 : 0; r.y = (b == ~0ULL) ? 1 : 0;
    return r;
}

// ---------------- fused prep: weight transpose | arena convert | degree histogram ----------------
struct CvtDesc { const void* src[9]; int cum[10]; };
struct TDesc { const void* baseL; const void* baseR; int L; };
__global__ __launch_bounds__(256) void k_prep(
    CvtDesc cd, TDesc td, const void* w0, const void* w1, const void* w2, const void* w3,
    const u16* __restrict__ xu, const long long* __restrict__ e64,
    const int* __restrict__ ei32, int E,
    u16* __restrict__ arena, int total, int* __restrict__ deg,
    u16* __restrict__ WT, int Tblocks, int Cblocks) {
    __shared__ u16 t[64][72];
    int2 fl = detect_inline(xu, e64);
    int bx = (int)blockIdx.x;
    if (bx < Tblocks) {
        int m = bx >> 4, tl = bx & 15;
        int tr = (tl >> 2) * 64, tc = (tl & 3) * 64;
        const void* S;
        size_t eoff = 0;
        if (m < 4)             S = (m == 0) ? w0 : (m == 1) ? w1 : (m == 2) ? w2 : w3;
        else if (m < 4 + td.L) { S = td.baseL; eoff = (size_t)(m - 4) * DIM * DIM; }
        else                   { S = td.baseR; eoff = (size_t)(m - 4 - td.L) * DIM * DIM; }
        u16* D = WT + (size_t)m * DIM * DIM;
        int r = threadIdx.x >> 2, cs = (threadIdx.x & 3) * 16;
        size_t src_idx = eoff + (size_t)(tr + r) * 256 + tc + cs;
        if (fl.x) {
            const u16* S16 = (const u16*)S + src_idx;
            *(int4*)&t[r][cs]     = *(const int4*)S16;
            *(int4*)&t[r][cs + 8] = *(const int4*)(S16 + 8);
        } else {
            const float* SF = (const float*)S + src_idx;
            u16 tmp[16];
#pragma unroll
            for (int q = 0; q < 4; ++q) {
                float4 v = *(const float4*)(SF + q * 4);
                tmp[q * 4] = f2bf(v.x); tmp[q * 4 + 1] = f2bf(v.y);
                tmp[q * 4 + 2] = f2bf(v.z); tmp[q * 4 + 3] = f2bf(v.w);
            }
            *(int4*)&t[r][cs]     = *(const int4*)&tmp[0];
            *(int4*)&t[r][cs + 8] = *(const int4*)&tmp[8];
        }
        __syncthreads();
        u16 tmp[16];
#pragma unroll
        for (int j = 0; j < 16; ++j) tmp[j] = t[cs + j][r];
        *(int4*)&D[(tc + r) * 256 + tr + cs]     = *(int4*)&tmp[0];
        *(int4*)&D[(tc + r) * 256 + tr + cs + 8] = *(int4*)&tmp[8];
    } else if (bx < Tblocks + Cblocks) {
        int i = (bx - Tblocks) * 256 + threadIdx.x;
        if (i >= total) return;
        int t2 = 0;
        while (i >= cd.cum[t2 + 1]) ++t2;
        int j = i - cd.cum[t2];
        u16 v;
        if (fl.x) v = ((const u16*)cd.src[t2])[j];
        else      v = f2bf(((const float*)cd.src[t2])[j]);
        arena[i] = v;
    } else {
        int e = (bx - Tblocks - Cblocks) * 256 + threadIdx.x;
        if (e >= E) return;
        const long long* ei64 = (const long long*)ei32;
        int d = fl.y ? (int)ei64[E + e] : ei32[E + e];
        atomicAdd(&deg[d], 1);
    }
}

__global__ __launch_bounds__(1024) void k_scan(const int* __restrict__ deg,
                                               int* __restrict__ offs,
                                               int* __restrict__ cursor, int N, int E) {
    __shared__ int s[1024];
    int t = threadIdx.x;
    int P = (N + 1023) >> 10;
    int base = t * P;
    int run = 0;
    for (int j = 0; j < P; ++j) { int idx = base + j; if (idx < N) run += deg[idx]; }
    s[t] = run;
    __syncthreads();
    int total = run;
    for (int off = 1; off < 1024; off <<= 1) {
        int v = 0;
        if (t >= off) v = s[t - off];
        __syncthreads();
        if (t >= off) s[t] += v;
        __syncthreads();
    }
    int r = s[t] - total;
    for (int j = 0; j < P; ++j) {
        int idx = base + j;
        if (idx < N) { offs[idx] = r; cursor[idx] = r; r += deg[idx]; }
    }
    if (t == 0) offs[N] = E;
}

__global__ void k_fill(const int* __restrict__ ei32, const u16* __restrict__ xu,
                       int* __restrict__ cursor, int* __restrict__ csr, int E) {
    int2 fl = detect_inline(xu, (const long long*)ei32);
    int e = blockIdx.x * 256 + threadIdx.x;
    if (e >= E) return;
    const long long* ei64 = (const long long*)ei32;
    int s = fl.y ? (int)ei64[e]     : ei32[e];
    int d = fl.y ? (int)ei64[E + e] : ei32[E + e];
    int pos = atomicAdd(&cursor[d], 1);
    csr[pos] = s;
}

// ---------------- fused QKVS GEMM: qs[N][512] = Q|S bf16; kv8[N][512] fp8 ----------------
__global__ __launch_bounds__(256) void gemm_qkvs(
    const u16* __restrict__ x, const u16* __restrict__ WT,
    const u16* __restrict__ bias, u16* __restrict__ qs,
    u8* __restrict__ kv8, int M) {
    __shared__ __align__(16) u16 lds[16384];
    u16* As = lds;
    u16* Bs = lds + 8192;
    int tid = threadIdx.x, w = tid >> 6, lane = tid & 63;
    int l15 = lane & 15, quad = lane >> 4;
    int lr = lane >> 3, lc = lane & 7;
    int bm0 = blockIdx.x * 128, bn0 = blockIdx.y * 128;
    f32x4 acc[4][4];
#pragma unroll
    for (int a = 0; a < 4; ++a)
#pragma unroll
        for (int b = 0; b < 4; ++b) acc[a][b] = (f32x4){0.f, 0.f, 0.f, 0.f};

    for (int k0 = 0; k0 < 256; k0 += 64) {
#pragma unroll
        for (int j = 0; j < 4; ++j) {
            int ar = (w * 4 + j) * 8 + lr;
            int grow = bm0 + ar; if (grow >= M) grow = M - 1;
            gl_lds16(x + (size_t)grow * 256 + k0 + lc * 8, &As[(w * 4 + j) * 512]);
        }
#pragma unroll
        for (int j = 0; j < 4; ++j) {
            int nr = (w * 4 + j) * 8 + lr;
            gl_lds16(WT + (size_t)(bn0 + nr) * 256 + k0 + lc * 8, &Bs[(w * 4 + j) * 512]);
        }
        __syncthreads();
        int wm = w & 1, wn = w >> 1;
#pragma unroll
        for (int s = 0; s < 2; ++s) {
            bf16x8 a[4], b[4];
#pragma unroll
            for (int t = 0; t < 4; ++t)
                a[t] = *(const bf16x8*)&As[(wm * 64 + t * 16 + l15) * 64 + s * 32 + quad * 8];
#pragma unroll
            for (int t = 0; t < 4; ++t)
                b[t] = *(const bf16x8*)&Bs[(wn * 64 + t * 16 + l15) * 64 + s * 32 + quad * 8];
#pragma unroll
            for (int rt = 0; rt < 4; ++rt)
#pragma unroll
                for (int ct = 0; ct < 4; ++ct)
                    acc[rt][ct] = __builtin_amdgcn_mfma_f32_16x16x32_bf16(a[rt], b[ct], acc[rt][ct], 0, 0, 0);
        }
        __syncthreads();
    }
    int wm = w & 1, wn = w >> 1;
    u16* oL = lds + w * 4096;
#pragma unroll
    for (int rt = 0; rt < 4; ++rt)
#pragma unroll
        for (int ct = 0; ct < 4; ++ct) {
            int col = bn0 + wn * 64 + ct * 16 + l15;
            float bv = bf2f(bias[col]);
#pragma unroll
            for (int r = 0; r < 4; ++r)
                oL[(rt * 16 + quad * 4 + r) * 64 + ct * 16 + l15] = f2bf(acc[rt][ct][r] + bv);
        }
    __syncthreads();
    int c0 = bn0 + wn * 64 + lc * 8;
#pragma unroll
    for (int j = 0; j < 8; ++j) {
        int orow = j * 8 + lr;
        int grow = bm0 + wm * 64 + orow;
        if (grow < M) {
            int4 hv = *(const int4*)&oL[orow * 64 + lc * 8];
            if (c0 < 256) {
                *(int4*)&qs[(size_t)grow * 512 + c0] = hv;             // Q
            } else if (c0 < 768) {
                float f[8]; cvt8(hv, f);
                uint2 o8;
                o8.x = pack4(f[0], f[1], f[2], f[3]);
                o8.y = pack4(f[4], f[5], f[6], f[7]);
                *(uint2*)(kv8 + (size_t)grow * 512 + (c0 - 256)) = o8; // K|V fp8
            } else {
                *(int4*)&qs[(size_t)grow * 512 + (c0 - 512)] = hv;     // Skip
            }
        }
    }
}

// ---------------- fused attention: 8 lanes/edge, 8 edges/wave, fp8 K+V (R7 form) ----------------
__global__ __launch_bounds__(256) void k_attn(const u16* __restrict__ qs,
                                              const u8* __restrict__ kv8,
                                              const int* __restrict__ csr,
                                              const int* __restrict__ offs,
                                              u16* __restrict__ hb,
                                              u8* __restrict__ h8, int N) {
    int wv = threadIdx.x >> 6, lane = threadIdx.x & 63;
    int i = blockIdx.x * 4 + wv;
    if (i >= N) return;
    int sub = lane & 7, e8 = lane >> 3;
    size_t row = (size_t)i * 512;

    float qf[32];
    {
        const u16* qp = qs + row + sub * 32;
#pragma unroll
        for (int j = 0; j < 4; ++j) {
            int4 v = *(const int4*)(qp + j * 8);
            float t[8]; cvt8(v, t);
#pragma unroll
            for (int d = 0; d < 8; ++d) qf[j * 8 + d] = t[d] * 0.0625f;
        }
    }
    int e0 = offs[i], e1 = offs[i + 1];
    float m = -1e30f, denom = 0.f;
    float acc[32];
#pragma unroll
    for (int j = 0; j < 32; ++j) acc[j] = 0.f;

    for (int base = e0; base < e1; base += 8) {
        int e = base + e8;
        int sidx = csr[(e < e1) ? e : (e1 - 1)];
        const u8* kp = kv8 + (size_t)sidx * 512 + sub * 32;
        uint4 ka = *(const uint4*)kp;
        uint4 kb = *(const uint4*)(kp + 16);
        uint4 va = *(const uint4*)(kp + 256);
        uint4 vb = *(const uint4*)(kp + 272);
        unsigned kw[8] = {ka.x, ka.y, ka.z, ka.w, kb.x, kb.y, kb.z, kb.w};
        float p = 0.f;
#pragma unroll
        for (int j = 0; j < 8; ++j) {
            float t[4]; dec4(kw[j], t);
            p += qf[j * 4] * t[0] + qf[j * 4 + 1] * t[1] + qf[j * 4 + 2] * t[2] + qf[j * 4 + 3] * t[3];
        }
        p += __shfl_xor(p, 1, 64);
        p += __shfl_xor(p, 2, 64);
        p += __shfl_xor(p, 4, 64);
        if (e >= e1) p = -1e30f;
        float pm = p;
        pm = fmaxf(pm, __shfl_xor(pm, 8, 64));
        pm = fmaxf(pm, __shfl_xor(pm, 16, 64));
        pm = fmaxf(pm, __shfl_xor(pm, 32, 64));
        if (pm > m) {
            float sc = __expf(m - pm);
            denom *= sc;
#pragma unroll
            for (int j = 0; j < 32; ++j) acc[j] *= sc;
            m = pm;
        }
        float w = __expf(p - m);
        denom += w;
        unsigned vw[8] = {va.x, va.y, va.z, va.w, vb.x, vb.y, vb.z, vb.w};
#pragma unroll
        for (int j = 0; j < 8; ++j) {
            float t[4]; dec4(vw[j], t);
            acc[j * 4]     += w * t[0];
            acc[j * 4 + 1] += w * t[1];
            acc[j * 4 + 2] += w * t[2];
            acc[j * 4 + 3] += w * t[3];
        }
    }
    denom += __shfl_xor(denom, 8, 64);
    denom += __shfl_xor(denom, 16, 64);
    denom += __shfl_xor(denom, 32, 64);
    float inv = (denom > 0.f) ? 1.f / denom : 0.f;
#pragma unroll
    for (int j = 0; j < 32; ++j) {
        acc[j] += __shfl_xor(acc[j], 8, 64);
        acc[j] += __shfl_xor(acc[j], 16, 64);
        acc[j] += __shfl_xor(acc[j], 32, 64);
    }
    if (e8 == 0) {
        const u16* skp = qs + row + 256 + sub * 32;
        float h[32];
#pragma unroll
        for (int j = 0; j < 4; ++j) {
            int4 sv = *(const int4*)(skp + j * 8);
            float t[8]; cvt8(sv, t);
            u16 o[8];
#pragma unroll
            for (int d = 0; d < 8; ++d) {
                float hv = fmaxf(acc[j * 8 + d] * inv + t[d], 0.f);
                h[j * 8 + d] = hv;
                o[d] = f2bf(hv);
            }
            *(int4*)(hb + (size_t)i * 256 + sub * 32 + j * 8) = *(const int4*)o;
        }
        uint4 p0, p1;
        p0.x = pack4(h[0], h[1], h[2], h[3]);   p0.y = pack4(h[4], h[5], h[6], h[7]);
        p0.z = pack4(h[8], h[9], h[10], h[11]); p0.w = pack4(h[12], h[13], h[14], h[15]);
        p1.x = pack4(h[16], h[17], h[18], h[19]); p1.y = pack4(h[20], h[21], h[22], h[23]);
        p1.z = pack4(h[24], h[25], h[26], h[27]); p1.w = pack4(h[28], h[29], h[30], h[31]);
        *(uint4*)(h8 + (size_t)i * 256 + sub * 32) = p0;
        *(uint4*)(h8 + (size_t)i * 256 + sub * 32 + 16) = p1;
    }
}

// ---------------- SAGE mean: one wave per node, 4 edges x 16 lanes x uint4 (R7 form) ----------------
__global__ __launch_bounds__(256) void k_agg(const u8* __restrict__ h8,
                                             const int* __restrict__ csr,
                                             const int* __restrict__ offs,
                                             u16* __restrict__ mean_out, int N) {
    int w = threadIdx.x >> 6, lane = threadIdx.x & 63;
    int i = blockIdx.x * 4 + w;
    if (i >= N) return;
    int g = lane >> 4, sub = lane & 15;
    int e0 = offs[i], e1 = offs[i + 1];
    float acc[16];
#pragma unroll
    for (int d = 0; d < 16; ++d) acc[d] = 0.f;
    int e = e0;
    for (; e + 8 <= e1; e += 8) {
        int s0 = csr[e + g], s1 = csr[e + 4 + g];
        uint4 r0 = *(const uint4*)(h8 + (size_t)s0 * 256 + sub * 16);
        uint4 r1 = *(const uint4*)(h8 + (size_t)s1 * 256 + sub * 16);
        float f0[16], f1[16];
        dec4(r0.x, f0); dec4(r0.y, f0 + 4); dec4(r0.z, f0 + 8); dec4(r0.w, f0 + 12);
        dec4(r1.x, f1); dec4(r1.y, f1 + 4); dec4(r1.z, f1 + 8); dec4(r1.w, f1 + 12);
#pragma unroll
        for (int d = 0; d < 16; ++d) acc[d] += f0[d] + f1[d];
    }
    for (; e + 4 <= e1; e += 4) {
        int s0 = csr[e + g];
        uint4 r0 = *(const uint4*)(h8 + (size_t)s0 * 256 + sub * 16);
        float f0[16];
        dec4(r0.x, f0); dec4(r0.y, f0 + 4); dec4(r0.z, f0 + 8); dec4(r0.w, f0 + 12);
#pragma unroll
        for (int d = 0; d < 16; ++d) acc[d] += f0[d];
    }
    if (e + g < e1) {
        int s0 = csr[e + g];
        uint4 r0 = *(const uint4*)(h8 + (size_t)s0 * 256 + sub * 16);
        float f0[16];
        dec4(r0.x, f0); dec4(r0.y, f0 + 4); dec4(r0.z, f0 + 8); dec4(r0.w, f0 + 12);
#pragma unroll
        for (int d = 0; d < 16; ++d) acc[d] += f0[d];
    }
#pragma unroll
    for (int d = 0; d < 16; ++d) {
        acc[d] += __shfl_xor(acc[d], 16, 64);
        acc[d] += __shfl_xor(acc[d], 32, 64);
    }
    if (g == 0) {
        int dg = e1 - e0; if (dg < 1) dg = 1;
        float inv = 1.f / (float)dg;
        u16 o16[16];
#pragma unroll
        for (int d = 0; d < 16; ++d) o16[d] = f2bf(acc[d] * inv);
        u16* dst = mean_out + (size_t)i * 256 + sub * 16;
        *(int4*)dst = *(const int4*)&o16[0];
        *(int4*)(dst + 8) = *(const int4*)&o16[8];
    }
}

// ---------------- SAGE GEMM (K=512) + BN / gated residual / relu ----------------
__global__ __launch_bounds__(256) void gemm_sage(
    const u16* __restrict__ meanA, const u16* __restrict__ hin,
    const u16* __restrict__ WlT, const u16* __restrict__ WrT,
    const u16* __restrict__ bl, const u16* __restrict__ gamma,
    const u16* __restrict__ beta, const u16* __restrict__ alpha,
    u16* __restrict__ hout, u8* __restrict__ h8out, float* __restrict__ fout, int M) {
    __shared__ __align__(16) u16 lds[12288];
    u16* As = lds;
    u16* Bs = lds + 8192;
    int tid = threadIdx.x, w = tid >> 6, lane = tid & 63;
    int l15 = lane & 15, quad = lane >> 4;
    int lr = lane >> 3, lc = lane & 7;
    int bm0 = blockIdx.x * 128, n0 = blockIdx.y * 64;
    f32x4 acc[2][4];
#pragma unroll
    for (int a = 0; a < 2; ++a)
#pragma unroll
        for (int b = 0; b < 4; ++b) acc[a][b] = (f32x4){0.f, 0.f, 0.f, 0.f};

    for (int k0 = 0; k0 < 512; k0 += 64) {
        const u16* Asrc = (k0 < 256) ? meanA : hin;
        const u16* Bsrc = (k0 < 256) ? WlT : WrT;
        int kc = k0 & 255;
#pragma unroll
        for (int j = 0; j < 4; ++j) {
            int ar = (w * 4 + j) * 8 + lr;
            int grow = bm0 + ar; if (grow >= M) grow = M - 1;
            gl_lds16(Asrc + (size_t)grow * 256 + kc + lc * 8, &As[(w * 4 + j) * 512]);
        }
#pragma unroll
        for (int j = 0; j < 2; ++j) {
            int nr = (w * 2 + j) * 8 + lr;
            gl_lds16(Bsrc + (size_t)(n0 + nr) * 256 + kc + lc * 8, &Bs[(w * 2 + j) * 512]);
        }
        __syncthreads();
#pragma unroll
        for (int s = 0; s < 2; ++s) {
            bf16x8 a[2], b[4];
#pragma unroll
            for (int t = 0; t < 2; ++t)
                a[t] = *(const bf16x8*)&As[(w * 32 + t * 16 + l15) * 64 + s * 32 + quad * 8];
#pragma unroll
            for (int t = 0; t < 4; ++t)
                b[t] = *(const bf16x8*)&Bs[(t * 16 + l15) * 64 + s * 32 + quad * 8];
#pragma unroll
            for (int rt = 0; rt < 2; ++rt)
#pragma unroll
                for (int ct = 0; ct < 4; ++ct)
                    acc[rt][ct] = __builtin_amdgcn_mfma_f32_16x16x32_bf16(a[rt], b[ct], acc[rt][ct], 0, 0, 0);
        }
        __syncthreads();
    }

    float al = 1.f / (1.f + __expf(-bf2f(alpha[0])));
    float alc = 1.f - al;
    u16* oL = lds + w * 2048;
#pragma unroll
    for (int rt = 0; rt < 2; ++rt)
#pragma unroll
        for (int ct = 0; ct < 4; ++ct) {
            int col = n0 + ct * 16 + l15;
            float g  = bf2f(gamma[col]) * BN_SCALE;
            float be = bf2f(beta[col]);
            float bb = bf2f(bl[col]);
#pragma unroll
            for (int r = 0; r < 4; ++r) {
                int grow = bm0 + w * 32 + rt * 16 + quad * 4 + r;
                float z = (acc[rt][ct][r] + bb) * g + be;
                float prev = (grow < M) ? bf2f(hin[(size_t)grow * 256 + col]) : 0.f;
                z = al * z + alc * prev;
                z = fmaxf(z, 0.f);
                oL[(rt * 16 + quad * 4 + r) * 64 + ct * 16 + l15] = f2bf(z);
                if (fout && grow < M) fout[(size_t)grow * 256 + col] = z;
            }
        }
    if (!hout) return;
    __syncthreads();
#pragma unroll
    for (int j = 0; j < 4; ++j) {
        int orow = j * 8 + lr;
        int grow = bm0 + w * 32 + orow;
        if (grow < M) {
            int4 hv = *(const int4*)&oL[orow * 64 + lc * 8];
            *(int4*)&hout[(size_t)grow * 256 + n0 + lc * 8] = hv;
            float f[8]; cvt8(hv, f);
            uint2 o8;
            o8.x = pack4(f[0], f[1], f[2], f[3]);
            o8.y = pack4(f[4], f[5], f[6], f[7]);
            *(uint2*)(h8out + (size_t)grow * 256 + n0 + lc * 8) = o8;
        }
    }
}

extern "C" void kernel_launch(void* const* d_in, const int* in_sizes, int n_in,
                              void* d_out, int out_size, void* d_ws, size_t ws_size,
                              hipStream_t stream) {
    int N = in_sizes[0] / DIM;
    int E = in_sizes[1] / 2;
    int L = in_sizes[10] / (DIM * DIM);

    const u16* xu = (const u16*)d_in[0];
    const long long* e64 = (const long long*)d_in[1];

    const int map9[9] = {0, 3, 5, 7, 9, 11, 13, 14, 15};
    CvtDesc cd;
    cd.cum[0] = 0;
    for (int t = 0; t < 9; ++t) {
        cd.src[t] = d_in[map9[t]];
        cd.cum[t + 1] = cd.cum[t] + in_sizes[map9[t]];
    }
    int total = cd.cum[9];

    char* ws = (char*)d_ws;
    size_t off = 0;
    auto take = [&](size_t bytes) { size_t c = off; off = (off + bytes + 255) & ~255ULL; return c; };

    u16* arena  = (u16*)(ws + take((size_t)total * 2));
    u16* WT     = (u16*)(ws + take((size_t)(4 + 2 * L) * DIM * DIM * 2));
    int* csr    = (int*)(ws + take((size_t)E * 4));
    int* deg    = (int*)(ws + take((size_t)N * 4));
    int* offs   = (int*)(ws + take((size_t)(N + 1) * 4));
    int* cursor = (int*)(ws + take((size_t)N * 4));
    u16* hB0    = (u16*)(ws + take((size_t)N * DIM * 2));
    u8*  kv8    = (u8*)(ws + take((size_t)N * 512));
    u8*  h8     = (u8*)(ws + take((size_t)N * 256));
    u16* qs     = (u16*)(ws + take((size_t)N * 512 * 2));  // Q|S bf16; dead after k_attn
    u16* meanB  = qs;                                      // overlay (N*256 u16)
    u16* hB1    = qs + (size_t)N * DIM;                    // overlay (N*256 u16)
    (void)ws_size; (void)n_in; (void)out_size;

    const u16* xb    = arena + cd.cum[0];
    const u16* biasF = arena + cd.cum[1];   // bq|bk|bv|bs contiguous
    const u16* blb   = arena + cd.cum[5];
    const u16* gmb   = arena + cd.cum[6];
    const u16* btb   = arena + cd.cum[7];
    const u16* alb   = arena + cd.cum[8];

    hipMemsetAsync(deg, 0, (size_t)N * 4, stream);

    TDesc td;
    td.baseL = d_in[10]; td.baseR = d_in[12]; td.L = L;
    int Tblocks = (4 + 2 * L) * 16;
    int Cblocks = (total + 255) / 256;
    int Eblocks = (E + 255) / 256;
    k_prep<<<Tblocks + Cblocks + Eblocks, 256, 0, stream>>>(
        cd, td, d_in[2], d_in[4], d_in[6], d_in[8], xu, e64,
        (const int*)d_in[1], E, arena, total, deg, WT, Tblocks, Cblocks);

    k_scan<<<1, 1024, 0, stream>>>(deg, offs, cursor, N, E);
    k_fill<<<Eblocks, 256, 0, stream>>>((const int*)d_in[1], xu, cursor, csr, E);

    int Mb128 = (N + 127) / 128;
    gemm_qkvs<<<dim3(Mb128, 8), 256, 0, stream>>>(xb, WT, biasF, qs, kv8, N);
    k_attn<<<(N + 3) / 4, 256, 0, stream>>>(qs, kv8, csr, offs, hB0, h8, N);

    for (int l = 0; l < L; ++l) {
        const u16* hin = (l & 1) ? hB1 : hB0;
        u16* hout      = (l == L - 1) ? nullptr : ((l & 1) ? hB0 : hB1);
        u8*  h8o       = (l == L - 1) ? nullptr : h8;
        float* fout    = (l == L - 1) ? (float*)d_out : nullptr;
        k_agg<<<(N + 3) / 4, 256, 0, stream>>>(h8, csr, offs, meanB, N);
        gemm_sage<<<dim3(Mb128, 4), 256, 0, stream>>>(
            meanB, hin, WT + (size_t)(4 + l) * DIM * DIM, WT + (size_t)(4 + L + l) * DIM * DIM,
            blb + (size_t)l * DIM, gmb + (size_t)l * DIM, btb + (size_t)l * DIM,
            alb, hout, h8o, fout, N);
    }
}

// Round 10
// 282.657 us; speedup vs baseline: 1.0562x; 1.0241x over previous
//
#include <hip/hip_runtime.h>
#include <hip/hip_bf16.h>

typedef unsigned short u16;
typedef unsigned int u32;
typedef unsigned char u8;
typedef __bf16 bf16x8 __attribute__((ext_vector_type(8)));
typedef float f32x4 __attribute__((ext_vector_type(4)));
typedef float f32x2 __attribute__((ext_vector_type(2)));

#define DIM 256
#define BN_SCALE 0.9999950000374997f // 1/sqrt(1 + 1e-5)

__device__ __forceinline__ float bf2f(u16 u) {
    union { unsigned u; float f; } c; c.u = ((unsigned)u) << 16; return c.f;
}
__device__ __forceinline__ u16 f2bf(float f) {
    union { float f; unsigned u; } c; c.f = f;
    unsigned u = c.u;
    unsigned r = (u + 0x7FFFu + ((u >> 16) & 1u)) >> 16;  // RNE
    return (u16)r;
}
__device__ __forceinline__ float asf(unsigned u) {
    union { unsigned u; float f; } c; c.u = u; return c.f;
}
__device__ __forceinline__ void cvt8(int4 v, float* f) {
    unsigned a0 = (unsigned)v.x, a1 = (unsigned)v.y, a2 = (unsigned)v.z, a3 = (unsigned)v.w;
    f[0] = asf(a0 << 16); f[1] = asf(a0 & 0xFFFF0000u);
    f[2] = asf(a1 << 16); f[3] = asf(a1 & 0xFFFF0000u);
    f[4] = asf(a2 << 16); f[5] = asf(a2 & 0xFFFF0000u);
    f[6] = asf(a3 << 16); f[7] = asf(a3 & 0xFFFF0000u);
}
__device__ __forceinline__ void dec4(unsigned u, float* f) {
    f32x2 lo = __builtin_amdgcn_cvt_pk_f32_fp8((int)u, false);
    f32x2 hi = __builtin_amdgcn_cvt_pk_f32_fp8((int)u, true);
    f[0] = lo.x; f[1] = lo.y; f[2] = hi.x; f[3] = hi.y;
}
__device__ __forceinline__ unsigned pack4(float a, float b, float c, float d) {
    int u = __builtin_amdgcn_cvt_pk_fp8_f32(a, b, 0, false);
    u = __builtin_amdgcn_cvt_pk_fp8_f32(c, d, u, true);
    return (unsigned)u;
}
__device__ __forceinline__ void gl_lds16(const u16* g, u16* l) {
    __builtin_amdgcn_global_load_lds(
        (__attribute__((address_space(1))) const u32*)(const void*)g,
        (__attribute__((address_space(3))) u32*)(void*)l, 16, 0, 0);
}

// wave-uniform dtype detect: .x = floats-are-bf16, .y = edges-are-int64
__device__ __forceinline__ int2 detect_inline(const u16* __restrict__ xu,
                                              const long long* __restrict__ e64) {
    int lane = threadIdx.x & 63;
    int pl = 0;
#pragma unroll
    for (int j = 0; j < 4; ++j) {
        u16 u = xu[lane * 4 + j];
        int ex = (u >> 7) & 0xFF;
        pl += (u == 0 || (ex >= 115 && ex <= 131)) ? 1 : 0;
    }
#pragma unroll
    for (int o = 32; o; o >>= 1) pl += __shfl_xor(pl, o, 64);
    long long hi = e64[lane] >> 32;
    unsigned long long b = __ballot(hi == 0);
    int2 r; r.x = (pl >= 200) ? 1 : 0; r.y = (b == ~0ULL) ? 1 : 0;
    return r;
}

// ---------------- fused prep: weight transpose | arena convert | degree histogram ----------------
struct CvtDesc { const void* src[9]; int cum[10]; };
struct TDesc { const void* baseL; const void* baseR; int L; };
__global__ __launch_bounds__(256) void k_prep(
    CvtDesc cd, TDesc td, const void* w0, const void* w1, const void* w2, const void* w3,
    const u16* __restrict__ xu, const long long* __restrict__ e64,
    const int* __restrict__ ei32, int E,
    u16* __restrict__ arena, int total, int* __restrict__ deg,
    u16* __restrict__ WT, int Tblocks, int Cblocks) {
    __shared__ u16 t[64][72];
    int2 fl = detect_inline(xu, e64);
    int bx = (int)blockIdx.x;
    if (bx < Tblocks) {
        int m = bx >> 4, tl = bx & 15;
        int tr = (tl >> 2) * 64, tc = (tl & 3) * 64;
        const void* S;
        size_t eoff = 0;
        if (m < 4)             S = (m == 0) ? w0 : (m == 1) ? w1 : (m == 2) ? w2 : w3;
        else if (m < 4 + td.L) { S = td.baseL; eoff = (size_t)(m - 4) * DIM * DIM; }
        else                   { S = td.baseR; eoff = (size_t)(m - 4 - td.L) * DIM * DIM; }
        u16* D = WT + (size_t)m * DIM * DIM;
        int r = threadIdx.x >> 2, cs = (threadIdx.x & 3) * 16;
        size_t src_idx = eoff + (size_t)(tr + r) * 256 + tc + cs;
        if (fl.x) {
            const u16* S16 = (const u16*)S + src_idx;
            *(int4*)&t[r][cs]     = *(const int4*)S16;
            *(int4*)&t[r][cs + 8] = *(const int4*)(S16 + 8);
        } else {
            const float* SF = (const float*)S + src_idx;
            u16 tmp[16];
#pragma unroll
            for (int q = 0; q < 4; ++q) {
                float4 v = *(const float4*)(SF + q * 4);
                tmp[q * 4] = f2bf(v.x); tmp[q * 4 + 1] = f2bf(v.y);
                tmp[q * 4 + 2] = f2bf(v.z); tmp[q * 4 + 3] = f2bf(v.w);
            }
            *(int4*)&t[r][cs]     = *(const int4*)&tmp[0];
            *(int4*)&t[r][cs + 8] = *(const int4*)&tmp[8];
        }
        __syncthreads();
        u16 tmp[16];
#pragma unroll
        for (int j = 0; j < 16; ++j) tmp[j] = t[cs + j][r];
        *(int4*)&D[(tc + r) * 256 + tr + cs]     = *(int4*)&tmp[0];
        *(int4*)&D[(tc + r) * 256 + tr + cs + 8] = *(int4*)&tmp[8];
    } else if (bx < Tblocks + Cblocks) {
        int i = (bx - Tblocks) * 256 + threadIdx.x;
        if (i >= total) return;
        int t2 = 0;
        while (i >= cd.cum[t2 + 1]) ++t2;
        int j = i - cd.cum[t2];
        u16 v;
        if (fl.x) v = ((const u16*)cd.src[t2])[j];
        else      v = f2bf(((const float*)cd.src[t2])[j]);
        arena[i] = v;
    } else {
        int e = (bx - Tblocks - Cblocks) * 256 + threadIdx.x;
        if (e >= E) return;
        const long long* ei64 = (const long long*)ei32;
        int d = fl.y ? (int)ei64[E + e] : ei32[E + e];
        atomicAdd(&deg[d], 1);
    }
}

__global__ __launch_bounds__(1024) void k_scan(const int* __restrict__ deg,
                                               int* __restrict__ offs,
                                               int* __restrict__ cursor, int N, int E) {
    __shared__ int s[1024];
    int t = threadIdx.x;
    int P = (N + 1023) >> 10;
    int base = t * P;
    int run = 0;
    for (int j = 0; j < P; ++j) { int idx = base + j; if (idx < N) run += deg[idx]; }
    s[t] = run;
    __syncthreads();
    int total = run;
    for (int off = 1; off < 1024; off <<= 1) {
        int v = 0;
        if (t >= off) v = s[t - off];
        __syncthreads();
        if (t >= off) s[t] += v;
        __syncthreads();
    }
    int r = s[t] - total;
    for (int j = 0; j < P; ++j) {
        int idx = base + j;
        if (idx < N) { offs[idx] = r; cursor[idx] = r; r += deg[idx]; }
    }
    if (t == 0) offs[N] = E;
}

__global__ void k_fill(const int* __restrict__ ei32, const u16* __restrict__ xu,
                       int* __restrict__ cursor, int* __restrict__ csr, int E) {
    int2 fl = detect_inline(xu, (const long long*)ei32);
    int e = blockIdx.x * 256 + threadIdx.x;
    if (e >= E) return;
    const long long* ei64 = (const long long*)ei32;
    int s = fl.y ? (int)ei64[e]     : ei32[e];
    int d = fl.y ? (int)ei64[E + e] : ei32[E + e];
    int pos = atomicAdd(&cursor[d], 1);
    csr[pos] = s;
}

// ---------------- fused QKVS GEMM: qs[N][512] = Q|S bf16; kv8[N][512] fp8 ----------------
__global__ __launch_bounds__(256) void gemm_qkvs(
    const u16* __restrict__ x, const u16* __restrict__ WT,
    const u16* __restrict__ bias, u16* __restrict__ qs,
    u8* __restrict__ kv8, int M) {
    __shared__ __align__(16) u16 lds[16384];
    u16* As = lds;
    u16* Bs = lds + 8192;
    int tid = threadIdx.x, w = tid >> 6, lane = tid & 63;
    int l15 = lane & 15, quad = lane >> 4;
    int lr = lane >> 3, lc = lane & 7;
    int bm0 = blockIdx.x * 128, bn0 = blockIdx.y * 128;
    f32x4 acc[4][4];
#pragma unroll
    for (int a = 0; a < 4; ++a)
#pragma unroll
        for (int b = 0; b < 4; ++b) acc[a][b] = (f32x4){0.f, 0.f, 0.f, 0.f};

    for (int k0 = 0; k0 < 256; k0 += 64) {
#pragma unroll
        for (int j = 0; j < 4; ++j) {
            int ar = (w * 4 + j) * 8 + lr;
            int grow = bm0 + ar; if (grow >= M) grow = M - 1;
            gl_lds16(x + (size_t)grow * 256 + k0 + lc * 8, &As[(w * 4 + j) * 512]);
        }
#pragma unroll
        for (int j = 0; j < 4; ++j) {
            int nr = (w * 4 + j) * 8 + lr;
            gl_lds16(WT + (size_t)(bn0 + nr) * 256 + k0 + lc * 8, &Bs[(w * 4 + j) * 512]);
        }
        __syncthreads();
        int wm = w & 1, wn = w >> 1;
#pragma unroll
        for (int s = 0; s < 2; ++s) {
            bf16x8 a[4], b[4];
#pragma unroll
            for (int t = 0; t < 4; ++t)
                a[t] = *(const bf16x8*)&As[(wm * 64 + t * 16 + l15) * 64 + s * 32 + quad * 8];
#pragma unroll
            for (int t = 0; t < 4; ++t)
                b[t] = *(const bf16x8*)&Bs[(wn * 64 + t * 16 + l15) * 64 + s * 32 + quad * 8];
#pragma unroll
            for (int rt = 0; rt < 4; ++rt)
#pragma unroll
                for (int ct = 0; ct < 4; ++ct)
                    acc[rt][ct] = __builtin_amdgcn_mfma_f32_16x16x32_bf16(a[rt], b[ct], acc[rt][ct], 0, 0, 0);
        }
        __syncthreads();
    }
    int wm = w & 1, wn = w >> 1;
    u16* oL = lds + w * 4096;
#pragma unroll
    for (int rt = 0; rt < 4; ++rt)
#pragma unroll
        for (int ct = 0; ct < 4; ++ct) {
            int col = bn0 + wn * 64 + ct * 16 + l15;
            float bv = bf2f(bias[col]);
#pragma unroll
            for (int r = 0; r < 4; ++r)
                oL[(rt * 16 + quad * 4 + r) * 64 + ct * 16 + l15] = f2bf(acc[rt][ct][r] + bv);
        }
    __syncthreads();
    int c0 = bn0 + wn * 64 + lc * 8;
#pragma unroll
    for (int j = 0; j < 8; ++j) {
        int orow = j * 8 + lr;
        int grow = bm0 + wm * 64 + orow;
        if (grow < M) {
            int4 hv = *(const int4*)&oL[orow * 64 + lc * 8];
            if (c0 < 256) {
                *(int4*)&qs[(size_t)grow * 512 + c0] = hv;             // Q
            } else if (c0 < 768) {
                float f[8]; cvt8(hv, f);
                uint2 o8;
                o8.x = pack4(f[0], f[1], f[2], f[3]);
                o8.y = pack4(f[4], f[5], f[6], f[7]);
                *(uint2*)(kv8 + (size_t)grow * 512 + (c0 - 256)) = o8; // K|V fp8
            } else {
                *(int4*)&qs[(size_t)grow * 512 + (c0 - 512)] = hv;     // Skip
            }
        }
    }
}

// ---------------- fused attention: 8 lanes/edge, 8 edges/wave, fp8 K+V ----------------
__global__ __launch_bounds__(256) void k_attn(const u16* __restrict__ qs,
                                              const u8* __restrict__ kv8,
                                              const int* __restrict__ csr,
                                              const int* __restrict__ offs,
                                              u16* __restrict__ hb,
                                              u8* __restrict__ h8, int N) {
    int wv = threadIdx.x >> 6, lane = threadIdx.x & 63;
    int i = blockIdx.x * 4 + wv;
    if (i >= N) return;
    int sub = lane & 7, e8 = lane >> 3;
    size_t row = (size_t)i * 512;

    float qf[32];
    {
        const u16* qp = qs + row + sub * 32;
#pragma unroll
        for (int j = 0; j < 4; ++j) {
            int4 v = *(const int4*)(qp + j * 8);
            float t[8]; cvt8(v, t);
#pragma unroll
            for (int d = 0; d < 8; ++d) qf[j * 8 + d] = t[d] * 0.0625f;
        }
    }
    int e0 = offs[i], e1 = offs[i + 1];
    float m = -1e30f, denom = 0.f;
    float acc[32];
#pragma unroll
    for (int j = 0; j < 32; ++j) acc[j] = 0.f;

    for (int base = e0; base < e1; base += 8) {
        int e = base + e8;
        int sidx = csr[(e < e1) ? e : (e1 - 1)];
        const u8* kp = kv8 + (size_t)sidx * 512 + sub * 32;
        uint4 ka = *(const uint4*)kp;
        uint4 kb = *(const uint4*)(kp + 16);
        uint4 va = *(const uint4*)(kp + 256);
        uint4 vb = *(const uint4*)(kp + 272);
        unsigned kw[8] = {ka.x, ka.y, ka.z, ka.w, kb.x, kb.y, kb.z, kb.w};
        float p = 0.f;
#pragma unroll
        for (int j = 0; j < 8; ++j) {
            float t[4]; dec4(kw[j], t);
            p += qf[j * 4] * t[0] + qf[j * 4 + 1] * t[1] + qf[j * 4 + 2] * t[2] + qf[j * 4 + 3] * t[3];
        }
        p += __shfl_xor(p, 1, 64);
        p += __shfl_xor(p, 2, 64);
        p += __shfl_xor(p, 4, 64);
        if (e >= e1) p = -1e30f;
        float pm = p;
        pm = fmaxf(pm, __shfl_xor(pm, 8, 64));
        pm = fmaxf(pm, __shfl_xor(pm, 16, 64));
        pm = fmaxf(pm, __shfl_xor(pm, 32, 64));
        if (pm > m) {
            float sc = __expf(m - pm);
            denom *= sc;
#pragma unroll
            for (int j = 0; j < 32; ++j) acc[j] *= sc;
            m = pm;
        }
        float w = __expf(p - m);
        denom += w;
        unsigned vw[8] = {va.x, va.y, va.z, va.w, vb.x, vb.y, vb.z, vb.w};
#pragma unroll
        for (int j = 0; j < 8; ++j) {
            float t[4]; dec4(vw[j], t);
            acc[j * 4]     += w * t[0];
            acc[j * 4 + 1] += w * t[1];
            acc[j * 4 + 2] += w * t[2];
            acc[j * 4 + 3] += w * t[3];
        }
    }
    denom += __shfl_xor(denom, 8, 64);
    denom += __shfl_xor(denom, 16, 64);
    denom += __shfl_xor(denom, 32, 64);
    float inv = (denom > 0.f) ? 1.f / denom : 0.f;
#pragma unroll
    for (int j = 0; j < 32; ++j) {
        acc[j] += __shfl_xor(acc[j], 8, 64);
        acc[j] += __shfl_xor(acc[j], 16, 64);
        acc[j] += __shfl_xor(acc[j], 32, 64);
    }
    if (e8 == 0) {
        const u16* skp = qs + row + 256 + sub * 32;
        float h[32];
#pragma unroll
        for (int j = 0; j < 4; ++j) {
            int4 sv = *(const int4*)(skp + j * 8);
            float t[8]; cvt8(sv, t);
            u16 o[8];
#pragma unroll
            for (int d = 0; d < 8; ++d) {
                float hv = fmaxf(acc[j * 8 + d] * inv + t[d], 0.f);
                h[j * 8 + d] = hv;
                o[d] = f2bf(hv);
            }
            *(int4*)(hb + (size_t)i * 256 + sub * 32 + j * 8) = *(const int4*)o;
        }
        uint4 p0, p1;
        p0.x = pack4(h[0], h[1], h[2], h[3]);   p0.y = pack4(h[4], h[5], h[6], h[7]);
        p0.z = pack4(h[8], h[9], h[10], h[11]); p0.w = pack4(h[12], h[13], h[14], h[15]);
        p1.x = pack4(h[16], h[17], h[18], h[19]); p1.y = pack4(h[20], h[21], h[22], h[23]);
        p1.z = pack4(h[24], h[25], h[26], h[27]); p1.w = pack4(h[28], h[29], h[30], h[31]);
        *(uint4*)(h8 + (size_t)i * 256 + sub * 32) = p0;
        *(uint4*)(h8 + (size_t)i * 256 + sub * 32 + 16) = p1;
    }
}

// ---------------- SAGE mean: one wave per node, 4 edges x 16 lanes x uint4 ----------------
__global__ __launch_bounds__(256) void k_agg(const u8* __restrict__ h8,
                                             const int* __restrict__ csr,
                                             const int* __restrict__ offs,
                                             u16* __restrict__ mean_out, int N) {
    int w = threadIdx.x >> 6, lane = threadIdx.x & 63;
    int i = blockIdx.x * 4 + w;
    if (i >= N) return;
    int g = lane >> 4, sub = lane & 15;
    int e0 = offs[i], e1 = offs[i + 1];
    float acc[16];
#pragma unroll
    for (int d = 0; d < 16; ++d) acc[d] = 0.f;
    int e = e0;
    for (; e + 8 <= e1; e += 8) {
        int s0 = csr[e + g], s1 = csr[e + 4 + g];
        uint4 r0 = *(const uint4*)(h8 + (size_t)s0 * 256 + sub * 16);
        uint4 r1 = *(const uint4*)(h8 + (size_t)s1 * 256 + sub * 16);
        float f0[16], f1[16];
        dec4(r0.x, f0); dec4(r0.y, f0 + 4); dec4(r0.z, f0 + 8); dec4(r0.w, f0 + 12);
        dec4(r1.x, f1); dec4(r1.y, f1 + 4); dec4(r1.z, f1 + 8); dec4(r1.w, f1 + 12);
#pragma unroll
        for (int d = 0; d < 16; ++d) acc[d] += f0[d] + f1[d];
    }
    for (; e + 4 <= e1; e += 4) {
        int s0 = csr[e + g];
        uint4 r0 = *(const uint4*)(h8 + (size_t)s0 * 256 + sub * 16);
        float f0[16];
        dec4(r0.x, f0); dec4(r0.y, f0 + 4); dec4(r0.z, f0 + 8); dec4(r0.w, f0 + 12);
#pragma unroll
        for (int d = 0; d < 16; ++d) acc[d] += f0[d];
    }
    if (e + g < e1) {
        int s0 = csr[e + g];
        uint4 r0 = *(const uint4*)(h8 + (size_t)s0 * 256 + sub * 16);
        float f0[16];
        dec4(r0.x, f0); dec4(r0.y, f0 + 4); dec4(r0.z, f0 + 8); dec4(r0.w, f0 + 12);
#pragma unroll
        for (int d = 0; d < 16; ++d) acc[d] += f0[d];
    }
#pragma unroll
    for (int d = 0; d < 16; ++d) {
        acc[d] += __shfl_xor(acc[d], 16, 64);
        acc[d] += __shfl_xor(acc[d], 32, 64);
    }
    if (g == 0) {
        int dg = e1 - e0; if (dg < 1) dg = 1;
        float inv = 1.f / (float)dg;
        u16 o16[16];
#pragma unroll
        for (int d = 0; d < 16; ++d) o16[d] = f2bf(acc[d] * inv);
        u16* dst = mean_out + (size_t)i * 256 + sub * 16;
        *(int4*)dst = *(const int4*)&o16[0];
        *(int4*)(dst + 8) = *(const int4*)&o16[8];
    }
}

// ---------------- SAGE GEMM (K=512) + BN / gated residual / relu ----------------
// 64(M) x 64(N) tile: grid (ceil(M/64), 4) = ~628 blocks -> 2.45/CU load balance
// (128-tile gave 316 blocks = worst-CU 2x block-time; 64-tile worst-CU 3 x half = 1.5x)
__global__ __launch_bounds__(256) void gemm_sage(
    const u16* __restrict__ meanA, const u16* __restrict__ hin,
    const u16* __restrict__ WlT, const u16* __restrict__ WrT,
    const u16* __restrict__ bl, const u16* __restrict__ gamma,
    const u16* __restrict__ beta, const u16* __restrict__ alpha,
    u16* __restrict__ hout, u8* __restrict__ h8out, float* __restrict__ fout, int M) {
    __shared__ __align__(16) u16 lds[8192];      // As [0,4096) 64x64; Bs [4096,8192) 64x64
    u16* As = lds;
    u16* Bs = lds + 4096;
    int tid = threadIdx.x, w = tid >> 6, lane = tid & 63;
    int l15 = lane & 15, quad = lane >> 4;
    int lr = lane >> 3, lc = lane & 7;
    int bm0 = blockIdx.x * 64, n0 = blockIdx.y * 64;
    f32x4 acc[4];
#pragma unroll
    for (int b = 0; b < 4; ++b) acc[b] = (f32x4){0.f, 0.f, 0.f, 0.f};

    for (int k0 = 0; k0 < 512; k0 += 64) {
        const u16* Asrc = (k0 < 256) ? meanA : hin;
        const u16* Bsrc = (k0 < 256) ? WlT : WrT;
        int kc = k0 & 255;
#pragma unroll
        for (int j = 0; j < 2; ++j) {           // wave stages 16 A-rows
            int ar = w * 16 + j * 8 + lr;
            int grow = bm0 + ar; if (grow >= M) grow = M - 1;
            gl_lds16(Asrc + (size_t)grow * 256 + kc + lc * 8, &As[(w * 2 + j) * 512]);
        }
#pragma unroll
        for (int j = 0; j < 2; ++j) {           // wave stages 16 B-rows (n-major)
            int nr = w * 16 + j * 8 + lr;
            gl_lds16(Bsrc + (size_t)(n0 + nr) * 256 + kc + lc * 8, &Bs[(w * 2 + j) * 512]);
        }
        __syncthreads();
#pragma unroll
        for (int s = 0; s < 2; ++s) {
            bf16x8 a = *(const bf16x8*)&As[(w * 16 + l15) * 64 + s * 32 + quad * 8];
            bf16x8 b[4];
#pragma unroll
            for (int t = 0; t < 4; ++t)
                b[t] = *(const bf16x8*)&Bs[(t * 16 + l15) * 64 + s * 32 + quad * 8];
#pragma unroll
            for (int ct = 0; ct < 4; ++ct)
                acc[ct] = __builtin_amdgcn_mfma_f32_16x16x32_bf16(a, b[ct], acc[ct], 0, 0, 0);
        }
        __syncthreads();
    }

    float al = 1.f / (1.f + __expf(-bf2f(alpha[0])));
    float alc = 1.f - al;
    u16* oL = lds + w * 1024;                   // 16x64 per wave (overlays As)
#pragma unroll
    for (int ct = 0; ct < 4; ++ct) {
        int col = n0 + ct * 16 + l15;
        float g  = bf2f(gamma[col]) * BN_SCALE;
        float be = bf2f(beta[col]);
        float bb = bf2f(bl[col]);
#pragma unroll
        for (int r = 0; r < 4; ++r) {
            int grow = bm0 + w * 16 + quad * 4 + r;
            float z = (acc[ct][r] + bb) * g + be;
            float prev = (grow < M) ? bf2f(hin[(size_t)grow * 256 + col]) : 0.f;
            z = al * z + alc * prev;
            z = fmaxf(z, 0.f);
            oL[(quad * 4 + r) * 64 + ct * 16 + l15] = f2bf(z);
            if (fout && grow < M) fout[(size_t)grow * 256 + col] = z;
        }
    }
    if (!hout) return;
    __syncthreads();
#pragma unroll
    for (int j = 0; j < 2; ++j) {
        int orow = j * 8 + lr;                  // 0..15 within wave's rows
        int grow = bm0 + w * 16 + orow;
        if (grow < M) {
            int4 hv = *(const int4*)&oL[orow * 64 + lc * 8];
            *(int4*)&hout[(size_t)grow * 256 + n0 + lc * 8] = hv;
            float f[8]; cvt8(hv, f);
            uint2 o8;
            o8.x = pack4(f[0], f[1], f[2], f[3]);
            o8.y = pack4(f[4], f[5], f[6], f[7]);
            *(uint2*)(h8out + (size_t)grow * 256 + n0 + lc * 8) = o8;
        }
    }
}

extern "C" void kernel_launch(void* const* d_in, const int* in_sizes, int n_in,
                              void* d_out, int out_size, void* d_ws, size_t ws_size,
                              hipStream_t stream) {
    int N = in_sizes[0] / DIM;
    int E = in_sizes[1] / 2;
    int L = in_sizes[10] / (DIM * DIM);

    const u16* xu = (const u16*)d_in[0];
    const long long* e64 = (const long long*)d_in[1];

    const int map9[9] = {0, 3, 5, 7, 9, 11, 13, 14, 15};
    CvtDesc cd;
    cd.cum[0] = 0;
    for (int t = 0; t < 9; ++t) {
        cd.src[t] = d_in[map9[t]];
        cd.cum[t + 1] = cd.cum[t] + in_sizes[map9[t]];
    }
    int total = cd.cum[9];

    char* ws = (char*)d_ws;
    size_t off = 0;
    auto take = [&](size_t bytes) { size_t c = off; off = (off + bytes + 255) & ~255ULL; return c; };

    u16* arena  = (u16*)(ws + take((size_t)total * 2));
    u16* WT     = (u16*)(ws + take((size_t)(4 + 2 * L) * DIM * DIM * 2));
    int* csr    = (int*)(ws + take((size_t)E * 4));
    int* deg    = (int*)(ws + take((size_t)N * 4));
    int* offs   = (int*)(ws + take((size_t)(N + 1) * 4));
    int* cursor = (int*)(ws + take((size_t)N * 4));
    u16* hB0    = (u16*)(ws + take((size_t)N * DIM * 2));
    u8*  kv8    = (u8*)(ws + take((size_t)N * 512));
    u8*  h8     = (u8*)(ws + take((size_t)N * 256));
    u16* qs     = (u16*)(ws + take((size_t)N * 512 * 2));  // Q|S bf16; dead after k_attn
    u16* meanB  = qs;                                      // overlay (N*256 u16)
    u16* hB1    = qs + (size_t)N * DIM;                    // overlay (N*256 u16)
    (void)ws_size; (void)n_in; (void)out_size;

    const u16* xb    = arena + cd.cum[0];
    const u16* biasF = arena + cd.cum[1];   // bq|bk|bv|bs contiguous
    const u16* blb   = arena + cd.cum[5];
    const u16* gmb   = arena + cd.cum[6];
    const u16* btb   = arena + cd.cum[7];
    const u16* alb   = arena + cd.cum[8];

    hipMemsetAsync(deg, 0, (size_t)N * 4, stream);

    TDesc td;
    td.baseL = d_in[10]; td.baseR = d_in[12]; td.L = L;
    int Tblocks = (4 + 2 * L) * 16;
    int Cblocks = (total + 255) / 256;
    int Eblocks = (E + 255) / 256;
    k_prep<<<Tblocks + Cblocks + Eblocks, 256, 0, stream>>>(
        cd, td, d_in[2], d_in[4], d_in[6], d_in[8], xu, e64,
        (const int*)d_in[1], E, arena, total, deg, WT, Tblocks, Cblocks);

    k_scan<<<1, 1024, 0, stream>>>(deg, offs, cursor, N, E);
    k_fill<<<Eblocks, 256, 0, stream>>>((const int*)d_in[1], xu, cursor, csr, E);

    int Mb128 = (N + 127) / 128;
    int Mb64  = (N + 63) / 64;
    gemm_qkvs<<<dim3(Mb128, 8), 256, 0, stream>>>(xb, WT, biasF, qs, kv8, N);
    k_attn<<<(N + 3) / 4, 256, 0, stream>>>(qs, kv8, csr, offs, hB0, h8, N);

    for (int l = 0; l < L; ++l) {
        const u16* hin = (l & 1) ? hB1 : hB0;
        u16* hout      = (l == L - 1) ? nullptr : ((l & 1) ? hB0 : hB1);
        u8*  h8o       = (l == L - 1) ? nullptr : h8;
        float* fout    = (l == L - 1) ? (float*)d_out : nullptr;
        k_agg<<<(N + 3) / 4, 256, 0, stream>>>(h8, csr, offs, meanB, N);
        gemm_sage<<<dim3(Mb64, 4), 256, 0, stream>>>(
            meanB, hin, WT + (size_t)(4 + l) * DIM * DIM, WT + (size_t)(4 + L + l) * DIM * DIM,
            blb + (size_t)l * DIM, gmb + (size_t)l * DIM, btb + (size_t)l * DIM,
            alb, hout, h8o, fout, N);
    }
}